// Round 3
// baseline (76.000 us; speedup 1.0000x reference)
//
#include <hip/hip_runtime.h>

#define HH 128
#define WW 128
#define CC 64
#define KD 16
#define HW (HH * WW)
#define HWB (HW * 4)
#define TOTBYTES (4u * CC * HW * 4u)   // B=4 * C=64 * H*W * 4B = 16 MB
#define OOB_SENT 0x40000000            // always-OOB voffset (no 32-bit wrap with soffset<=16.8M)

using int32x4_t = __attribute__((ext_vector_type(4))) int;
using floatx4   = __attribute__((ext_vector_type(4))) float;

__device__ floatx4 llvm_amdgcn_raw_buffer_load_v4f32(int32x4_t srsrc, int voffset,
                                                     int soffset, int aux)
    __asm("llvm.amdgcn.raw.buffer.load.v4f32");
__device__ float llvm_amdgcn_raw_buffer_load_f32(int32x4_t srsrc, int voffset,
                                                 int soffset, int aux)
    __asm("llvm.amdgcn.raw.buffer.load.f32");

__device__ inline int32x4_t make_srd(const void* p, unsigned bytes) {
    const unsigned long long a = (unsigned long long)p;
    int32x4_t r;
    r.x = (int)(a & 0xffffffffull);
    r.y = (int)(a >> 32);
    r.z = (int)bytes;
    r.w = 0x00020000;
    return r;
}

#if __has_builtin(__builtin_amdgcn_exp2f)
#define FAST_EXP2(x) __builtin_amdgcn_exp2f(x)
#define KLOG2E 1.44269504088896340736f
#else
#define FAST_EXP2(x) __expf(x)
#define KLOG2E 1.0f
#endif

// Block: 512 threads = 8 waves, all covering the SAME 16x4 pixel tile.
// Phase 1: wave g computes k[d] for d in {2g, 2g+1}  (c-loop over 64, weights SGPR-uniform).
// Phase 2: wave g handles channels c in [8g, 8g+8).
// Grid: (8, 32, 4) = 1024 blocks -> 4 blocks/CU = 32 waves/CU (full occupancy @ <=64 VGPR).
__global__ __launch_bounds__(512, 8) void gatev_fused(
    const float* __restrict__ x, const float* __restrict__ y,
    const float* __restrict__ z,
    const float* __restrict__ Wq, const float* __restrict__ bq,
    const float* __restrict__ Wk, const float* __restrict__ bk,
    const float* __restrict__ wv, const float* __restrict__ bv,
    float* __restrict__ out)
{
    __shared__ float k_lds[KD][64];    // d-major: phase-2 reads are lane-contiguous

    const int tid  = threadIdx.x;
    const int g    = __builtin_amdgcn_readfirstlane(tid >> 6);
    const int lane = tid & 63;
    const int px   = lane & 15, py = lane >> 4;
    const int b    = blockIdx.z;
    const int h    = blockIdx.y * 4 + py;
    const int w    = blockIdx.x * 16 + px;
    const int pix  = h * WW + w;

    const int32x4_t rx = make_srd(x, TOTBYTES);
    const int32x4_t ry = make_srd(y, TOTBYTES);
    const int32x4_t rz = make_srd(z, TOTBYTES);

    // One float4 per tap-row at col base max(w-1,0) covers all 3 horizontal taps.
    const int colb = (w > 0 ? w - 1 : 0) * 4;
    int rowB[3];
#pragma unroll
    for (int r = 0; r < 3; ++r) {
        const int rr = h - 1 + r;
        rowB[r] = (rr >= 0 && rr < HH) ? rr * WW * 4 + colb : OOB_SENT;
    }
    const float mL = (w > 0) ? 1.f : 0.f;
    const float mR = (w < WW - 1) ? 1.f : 0.f;
    const bool  w0 = (w == 0);

    const int base = b * CC * HWB;

    auto load3 = [&](const int32x4_t& srd, floatx4 (&f)[3], int so) {
#pragma unroll
        for (int r = 0; r < 3; ++r)
            f[r] = llvm_amdgcn_raw_buffer_load_v4f32(srd, rowB[r], so, 0);
    };
    // Extract the 3 taps of row r from the float4 (handles w==0 / w==127 edges).
    auto taps = [&](const floatx4& f, float& tL, float& tC, float& tR) {
        tL = f.x * mL;
        tC = w0 ? f.x : f.y;
        tR = (w0 ? f.y : f.z) * mR;
    };

    // ---------------- phase 1: k = relu(conv3x3(x) + bk), 2 d's per wave ----
    const int d0 = g * 2;
    const int wb = __builtin_amdgcn_readfirstlane(d0 * CC * 9);

    float a0 = 0.f, a1 = 0.f;
    floatx4 f0[3], f1[3];
    load3(rx, f0, base);

    auto accum = [&](const floatx4 (&f)[3], const float* wp) {
#pragma unroll
        for (int r = 0; r < 3; ++r) {
            float tL, tC, tR;
            taps(f[r], tL, tC, tR);
            a0 = fmaf(wp[r * 3 + 0], tL, a0);
            a0 = fmaf(wp[r * 3 + 1], tC, a0);
            a0 = fmaf(wp[r * 3 + 2], tR, a0);
            a1 = fmaf(wp[576 + r * 3 + 0], tL, a1);
            a1 = fmaf(wp[576 + r * 3 + 1], tC, a1);
            a1 = fmaf(wp[576 + r * 3 + 2], tR, a1);
        }
    };

    for (int c = 0; c < CC; c += 2) {
        const float* wp = Wk + wb + c * 9;
        load3(rx, f1, base + (c + 1) * HWB);   // prefetch c+1
        accum(f0, wp);
        load3(rx, f0, base + (c + 2) * HWB);   // prefetch c+2 (tail: OOB-zero or discarded)
        accum(f1, wp + 9);
    }

    k_lds[d0 + 0][lane] = fmaxf(a0 + bk[d0 + 0], 0.f) * KLOG2E;
    k_lds[d0 + 1][lane] = fmaxf(a1 + bk[d0 + 1], 0.f) * KLOG2E;
    __syncthreads();

    // ---------------- phase 2: q, v, softmax-attention, 8 c's per wave ------
    const int c0 = __builtin_amdgcn_readfirstlane(g * 8);

    float q[8], zv[8];
#pragma unroll 2
    for (int ci = 0; ci < 8; ++ci) {
        const int c  = c0 + ci;
        const int so = base + c * HWB;
        floatx4 fr[3];
        load3(ry, fr, so);
        const float* wq = Wq + c * 9;
        float acc = 0.f;
#pragma unroll
        for (int r = 0; r < 3; ++r) {
            float tL, tC, tR;
            taps(fr[r], tL, tC, tR);
            acc = fmaf(wq[r * 3 + 0], tL, acc);
            acc = fmaf(wq[r * 3 + 1], tC, acc);
            acc = fmaf(wq[r * 3 + 2], tR, acc);
        }
        q[ci]  = fmaxf(acc + bq[c], 0.f);
        zv[ci] = llvm_amdgcn_raw_buffer_load_f32(rz, pix * 4, so, 0);
    }

    float num[8], den[8];
#pragma unroll
    for (int ci = 0; ci < 8; ++ci) { num[ci] = 0.f; den[ci] = 0.f; }

#pragma unroll
    for (int d = 0; d < KD; ++d) {
        const float kl  = k_lds[d][lane];      // lane-contiguous: conflict-free
        const float wvd = wv[d];               // SGPR
        const float bvd = bv[d];               // SGPR
#pragma unroll
        for (int ci = 0; ci < 8; ++ci) {
            const float e = FAST_EXP2(q[ci] * kl);
            const float v = fmaxf(zv[ci] * wvd + bvd, 0.f);
            num[ci] = fmaf(e, v, num[ci]);
            den[ci] += e;
        }
    }

    float* ob = out + (size_t)base / 4;
#pragma unroll
    for (int ci = 0; ci < 8; ++ci)
        ob[(c0 + ci) * HW + pix] = __fdividef(num[ci], den[ci]);
}

extern "C" void kernel_launch(void* const* d_in, const int* in_sizes, int n_in,
                              void* d_out, int out_size, void* d_ws, size_t ws_size,
                              hipStream_t stream) {
    const float* x  = (const float*)d_in[0];
    const float* y  = (const float*)d_in[1];
    const float* z  = (const float*)d_in[2];
    const float* Wq = (const float*)d_in[3];
    const float* bq = (const float*)d_in[4];
    const float* Wk = (const float*)d_in[5];
    const float* bk = (const float*)d_in[6];
    const float* wv = (const float*)d_in[7];
    const float* bv = (const float*)d_in[8];
    float* out = (float*)d_out;

    dim3 grid(WW / 16, HH / 4, 4);   // 1024 blocks
    dim3 block(512);                 // 8 waves
    hipLaunchKernelGGL(gatev_fused, grid, block, 0, stream,
                       x, y, z, Wq, bq, Wk, bk, wv, bv, out);
}

// Round 4
// 51.178 us; speedup vs baseline: 1.4850x; 1.4850x over previous
//
#include <hip/hip_runtime.h>

#define HH 128
#define WW 128
#define CC 64
#define KD 16
#define HW (HH * WW)
#define HWB (HW * 4)
#define TOTBYTES (4u * CC * HW * 4u)   // B=4 * C=64 * H*W * 4B
#define OOB_SENT 0x40000000            // always-OOB voffset (tensor = 16.8 MB)

using int32x4_t = __attribute__((ext_vector_type(4))) int;
using floatx4   = __attribute__((ext_vector_type(4))) float;

__device__ floatx4 llvm_amdgcn_raw_buffer_load_v4f32(int32x4_t srsrc, int voffset,
                                                     int soffset, int aux)
    __asm("llvm.amdgcn.raw.buffer.load.v4f32");
__device__ float llvm_amdgcn_raw_buffer_load_f32(int32x4_t srsrc, int voffset,
                                                 int soffset, int aux)
    __asm("llvm.amdgcn.raw.buffer.load.f32");

__device__ inline int32x4_t make_srd(const void* p, unsigned bytes) {
    const unsigned long long a = (unsigned long long)p;
    int32x4_t r;
    r.x = (int)(a & 0xffffffffull);
    r.y = (int)(a >> 32);
    r.z = (int)bytes;
    r.w = 0x00020000;
    return r;
}

#if __has_builtin(__builtin_amdgcn_exp2f)
#define FAST_EXP2(x) __builtin_amdgcn_exp2f(x)
#define KLOG2E 1.44269504088896340736f
#else
#define FAST_EXP2(x) __expf(x)
#define KLOG2E 1.0f
#endif

// Block: 512 threads = 8 waves, all covering the SAME 16(w) x 4(h) pixel tile.
// Phase 1 (partial-sum split): wave g reads ONLY channels [8g,8g+8) of x and
//   accumulates partial k for ALL 16 d's -> LDS -> tree reduction.
//   x-tile is read exactly once per block (R3 read it 8x -> L1 thrash).
// Phase 2: wave g handles channels [8g,8g+8): q conv, v, softmax-attention.
// Grid: (8, 32, 4) = 1024 blocks = 4 blocks/CU.
__global__ __launch_bounds__(512, 8) void gatev_fused(
    const float* __restrict__ x, const float* __restrict__ y,
    const float* __restrict__ z,
    const float* __restrict__ Wq, const float* __restrict__ bq,
    const float* __restrict__ Wk, const float* __restrict__ bk,
    const float* __restrict__ wv, const float* __restrict__ bv,
    float* __restrict__ out)
{
    __shared__ float part[8 * KD * 64];   // 32 KB; part[0..KD*64) becomes k after reduction

    const int tid  = threadIdx.x;
    const int g    = __builtin_amdgcn_readfirstlane(tid >> 6);
    const int lane = tid & 63;
    const int px   = lane & 15, py = lane >> 4;
    const int b    = blockIdx.z;
    const int h    = blockIdx.y * 4 + py;
    const int w    = blockIdx.x * 16 + px;
    const int pix  = h * WW + w;

    const int32x4_t rx = make_srd(x, TOTBYTES);
    const int32x4_t ry = make_srd(y, TOTBYTES);
    const int32x4_t rz = make_srd(z, TOTBYTES);

    // One float4 per tap-row at col max(w-1,0) covers the 3 horizontal taps.
    const int colb = (w > 0 ? w - 1 : 0) * 4;
    int rowB[3];
#pragma unroll
    for (int r = 0; r < 3; ++r) {
        const int rr = h - 1 + r;
        rowB[r] = (rr >= 0 && rr < HH) ? rr * WW * 4 + colb : OOB_SENT;
    }
    const float mL = (w > 0) ? 1.f : 0.f;
    const float mR = (w < WW - 1) ? 1.f : 0.f;
    const bool  w0 = (w == 0);

    const int base = b * CC * HWB;
    const int c0   = __builtin_amdgcn_readfirstlane(g * 8);

    auto taps9 = [&](const int32x4_t& srd, int so, float (&tp)[9]) {
#pragma unroll
        for (int r = 0; r < 3; ++r) {
            const floatx4 f = llvm_amdgcn_raw_buffer_load_v4f32(srd, rowB[r], so, 0);
            tp[r * 3 + 0] = f.x * mL;
            tp[r * 3 + 1] = w0 ? f.x : f.y;
            tp[r * 3 + 2] = (w0 ? f.y : f.z) * mR;
        }
    };

    // ---------------- phase 1: partial k over this wave's 8 channels --------
    float acc[KD];
#pragma unroll
    for (int d = 0; d < KD; ++d) acc[d] = 0.f;

    for (int ci = 0; ci < 8; ++ci) {
        const int c = c0 + ci;
        float tp[9];
        taps9(rx, base + c * HWB, tp);
        const float* wp = Wk + c * 9;        // Wk[d][c][t] = wp[d*576 + t]; uniform -> s_load
#pragma unroll
        for (int d = 0; d < KD; ++d)
#pragma unroll
            for (int t = 0; t < 9; ++t)
                acc[d] = fmaf(wp[d * (CC * 9) + t], tp[t], acc[d]);
    }
#pragma unroll
    for (int d = 0; d < KD; ++d)
        part[g * (KD * 64) + d * 64 + lane] = acc[d];
    __syncthreads();

    // ---------------- reduce partials -> k[d][px] (in place, single-owner) --
#pragma unroll
    for (int rep = 0; rep < 2; ++rep) {
        const int idx = tid + rep * 512;     // = d*64 + px, in [0,1024)
        float s = part[idx];
#pragma unroll
        for (int gg = 1; gg < 8; ++gg) s += part[gg * (KD * 64) + idx];
        const int d = idx >> 6;              // wave-uniform
        part[idx] = fmaxf(s + bk[d], 0.f) * KLOG2E;
    }
    __syncthreads();

    // ---------------- phase 2: q, v, softmax-attention, 8 c's per wave ------
    float q[8], zv[8];
#pragma unroll 2
    for (int ci = 0; ci < 8; ++ci) {
        const int c  = c0 + ci;
        const int so = base + c * HWB;
        float tp[9];
        taps9(ry, so, tp);
        const float* wq = Wq + c * 9;        // uniform -> s_load
        float a = 0.f;
#pragma unroll
        for (int t = 0; t < 9; ++t) a = fmaf(wq[t], tp[t], a);
        q[ci]  = fmaxf(a + bq[c], 0.f);
        zv[ci] = llvm_amdgcn_raw_buffer_load_f32(rz, pix * 4, so, 0);
    }

    float num[8], den[8];
#pragma unroll
    for (int ci = 0; ci < 8; ++ci) { num[ci] = 0.f; den[ci] = 0.f; }

#pragma unroll
    for (int d = 0; d < KD; ++d) {
        const float kl  = part[d * 64 + lane];   // lane-contiguous: conflict-free
        const float wvd = wv[d];                 // SGPR
        const float bvd = bv[d];                 // SGPR
#pragma unroll
        for (int ci = 0; ci < 8; ++ci) {
            const float e = FAST_EXP2(q[ci] * kl);
            const float v = fmaxf(zv[ci] * wvd + bvd, 0.f);
            num[ci] = fmaf(e, v, num[ci]);
            den[ci] += e;
        }
    }

    float* ob = out + (size_t)b * CC * HW;
#pragma unroll
    for (int ci = 0; ci < 8; ++ci)
        ob[(c0 + ci) * HW + pix] = __fdividef(num[ci], den[ci]);
}

extern "C" void kernel_launch(void* const* d_in, const int* in_sizes, int n_in,
                              void* d_out, int out_size, void* d_ws, size_t ws_size,
                              hipStream_t stream) {
    const float* x  = (const float*)d_in[0];
    const float* y  = (const float*)d_in[1];
    const float* z  = (const float*)d_in[2];
    const float* Wq = (const float*)d_in[3];
    const float* bq = (const float*)d_in[4];
    const float* Wk = (const float*)d_in[5];
    const float* bk = (const float*)d_in[6];
    const float* wv = (const float*)d_in[7];
    const float* bv = (const float*)d_in[8];
    float* out = (float*)d_out;

    dim3 grid(WW / 16, HH / 4, 4);   // 1024 blocks
    dim3 block(512);                 // 8 waves
    hipLaunchKernelGGL(gatev_fused, grid, block, 0, stream,
                       x, y, z, Wq, bq, Wk, bk, wv, bv, out);
}